// Round 1
// baseline (2258.351 us; speedup 1.0000x reference)
//
#include <hip/hip_runtime.h>
#include <math.h>

// InteractionPPBlock (DimeNet++) — round 1: correct f32 pipeline.
// E=262144 edges, T=2097152 triplets, EMB=128, INT_EMB=64, BASIS=8,
// NUM_RADIAL=6, NUM_SPHERICAL=7 (42), N_BEFORE=1, N_AFTER=2.
//
// Kernels:
//  zero_kernel    : zero m_update accumulator (ws is poisoned 0xAA each call)
//  edge_kernel    : rbf_e, x_ji = silu(m@W_ji+b), x_kj = silu((silu(m@W_kj+b)*rbf_e)@W_down)
//  triplet_kernel : sbf_t = (sbf@W_sbf1)@W_sbf2; atomicAdd m_update[dst] += x_kj[src]*sbf_t
//  post_kernel    : silu(m_update@W_up)+x_ji -> residual(before) -> silu(@W_final+b)
//                   -> +m -> residual x2(after) -> out
//
// GEMM microkernel: 64-row tile, 256 threads, per-thread 8 rows x 4 cols,
// activations in LDS (float4 reads), weights streamed from global (L2-resident).

#define E_N 262144
#define T_N 2097152

__device__ __forceinline__ float silu_f(float x) {
    return x / (1.0f + __expf(-x));
}

// acc[8][4] = X[64][K](lds, ld=K) @ W[K][128](global); rows ty*8.., cols tx*4..
template<int K>
__device__ __forceinline__ void gemmK_128(const float* __restrict__ Xl,
                                          const float* __restrict__ W,
                                          int ty, int tx, float acc[8][4]) {
#pragma unroll
    for (int i = 0; i < 8; i++) {
        acc[i][0] = 0.f; acc[i][1] = 0.f; acc[i][2] = 0.f; acc[i][3] = 0.f;
    }
    const float4* __restrict__ W4 = (const float4*)W;
    const float4* __restrict__ X4 = (const float4*)Xl;
    for (int k4 = 0; k4 < K / 4; k4++) {
        float4 a4[8];
#pragma unroll
        for (int i = 0; i < 8; i++) a4[i] = X4[((ty * 8 + i) * K >> 2) + k4];
#pragma unroll
        for (int kk = 0; kk < 4; kk++) {
            float4 w = W4[(k4 * 4 + kk) * 32 + tx];
#pragma unroll
            for (int i = 0; i < 8; i++) {
                float a = kk == 0 ? a4[i].x : kk == 1 ? a4[i].y : kk == 2 ? a4[i].z : a4[i].w;
                acc[i][0] = fmaf(a, w.x, acc[i][0]);
                acc[i][1] = fmaf(a, w.y, acc[i][1]);
                acc[i][2] = fmaf(a, w.z, acc[i][2]);
                acc[i][3] = fmaf(a, w.w, acc[i][3]);
            }
        }
    }
}

__global__ __launch_bounds__(256) void zero_kernel(float4* __restrict__ p, int n4) {
    int i = blockIdx.x * 256 + threadIdx.x;
    if (i < n4) p[i] = make_float4(0.f, 0.f, 0.f, 0.f);
}

__global__ __launch_bounds__(256, 2) void edge_kernel(
    const float* __restrict__ m, const float* __restrict__ rbf,
    const float* __restrict__ W_rbf1, const float* __restrict__ W_rbf2,
    const float* __restrict__ W_ji, const float* __restrict__ b_ji,
    const float* __restrict__ W_kj, const float* __restrict__ b_kj,
    const float* __restrict__ W_down,
    float* __restrict__ x_ji, float* __restrict__ x_kj) {
    __shared__ float Mt[64 * 128];   // m tile
    __shared__ float At[64 * 128];   // rbf_e, then tmp = silu(m@W_kj+b)*rbf_e
    __shared__ float rraw[64 * 6];
    __shared__ float hb[64 * 8];
    const int tid = threadIdx.x;
    const int r0 = blockIdx.x * 64;

    {   // stage m tile (8192 floats = 2048 float4)
        const float4* src = (const float4*)(m + (size_t)r0 * 128);
        float4* dst = (float4*)Mt;
#pragma unroll
        for (int i = 0; i < 8; i++) dst[tid + i * 256] = src[tid + i * 256];
    }
    for (int i = tid; i < 64 * 6; i += 256) rraw[i] = rbf[(size_t)r0 * 6 + i];
    __syncthreads();

    {   // h = rbf @ W_rbf1  [64][8], 2 outputs/thread
        int tt = tid >> 2, b0 = (tid & 3) << 1;
        float s0 = 0.f, s1 = 0.f;
#pragma unroll
        for (int k = 0; k < 6; k++) {
            float v = rraw[tt * 6 + k];
            s0 = fmaf(v, W_rbf1[k * 8 + b0], s0);
            s1 = fmaf(v, W_rbf1[k * 8 + b0 + 1], s1);
        }
        hb[tt * 8 + b0] = s0;
        hb[tt * 8 + b0 + 1] = s1;
    }
    __syncthreads();

    const int ty = tid >> 5, tx = tid & 31;
    float acc[8][4];

    // rbf_e = h @ W_rbf2 -> At
    gemmK_128<8>(hb, W_rbf2, ty, tx, acc);
#pragma unroll
    for (int i = 0; i < 8; i++) {
        int r = ty * 8 + i;
        float4 v = make_float4(acc[i][0], acc[i][1], acc[i][2], acc[i][3]);
        ((float4*)At)[r * 32 + tx] = v;
    }

    // x_ji = silu(m @ W_ji + b_ji)
    {
        float4 b = ((const float4*)b_ji)[tx];
        gemmK_128<128>(Mt, W_ji, ty, tx, acc);
#pragma unroll
        for (int i = 0; i < 8; i++) {
            int r = ty * 8 + i;
            float4 v;
            v.x = silu_f(acc[i][0] + b.x);
            v.y = silu_f(acc[i][1] + b.y);
            v.z = silu_f(acc[i][2] + b.z);
            v.w = silu_f(acc[i][3] + b.w);
            ((float4*)x_ji)[(size_t)(r0 + r) * 32 + tx] = v;
        }
    }

    // tmp = silu(m @ W_kj + b_kj) * rbf_e -> At (each thread RMWs only its own elems)
    {
        float4 b = ((const float4*)b_kj)[tx];
        gemmK_128<128>(Mt, W_kj, ty, tx, acc);
#pragma unroll
        for (int i = 0; i < 8; i++) {
            int r = ty * 8 + i;
            float4 re = ((float4*)At)[r * 32 + tx];
            float4 v;
            v.x = silu_f(acc[i][0] + b.x) * re.x;
            v.y = silu_f(acc[i][1] + b.y) * re.y;
            v.z = silu_f(acc[i][2] + b.z) * re.z;
            v.w = silu_f(acc[i][3] + b.w) * re.w;
            ((float4*)At)[r * 32 + tx] = v;
        }
    }
    __syncthreads();

    // x_kj = silu(At @ W_down)  [64][64]
    {
        float a2[8][2];
#pragma unroll
        for (int i = 0; i < 8; i++) { a2[i][0] = 0.f; a2[i][1] = 0.f; }
        const float2* __restrict__ W2 = (const float2*)W_down;
        const float4* __restrict__ A4 = (const float4*)At;
        for (int k4 = 0; k4 < 32; k4++) {
            float4 a4[8];
#pragma unroll
            for (int i = 0; i < 8; i++) a4[i] = A4[(ty * 8 + i) * 32 + k4];
#pragma unroll
            for (int kk = 0; kk < 4; kk++) {
                float2 w = W2[(k4 * 4 + kk) * 32 + tx];
#pragma unroll
                for (int i = 0; i < 8; i++) {
                    float a = kk == 0 ? a4[i].x : kk == 1 ? a4[i].y : kk == 2 ? a4[i].z : a4[i].w;
                    a2[i][0] = fmaf(a, w.x, a2[i][0]);
                    a2[i][1] = fmaf(a, w.y, a2[i][1]);
                }
            }
        }
#pragma unroll
        for (int i = 0; i < 8; i++) {
            int r = ty * 8 + i;
            float2 v;
            v.x = silu_f(a2[i][0]);
            v.y = silu_f(a2[i][1]);
            ((float2*)x_kj)[(size_t)(r0 + r) * 32 + tx] = v;
        }
    }
}

__global__ __launch_bounds__(256, 4) void triplet_kernel(
    const float* __restrict__ sbf, const int* __restrict__ src_idx,
    const int* __restrict__ dst_idx,
    const float* __restrict__ W_sbf1, const float* __restrict__ W_sbf2,
    const float* __restrict__ x_kj, float* __restrict__ m_update) {
    __shared__ float S[64 * 42];
    __shared__ float B[64 * 8];
    __shared__ float W1l[42 * 8];
    const int tid = threadIdx.x;
    const int t0 = blockIdx.x * 64;

    {   // sbf tile: contiguous 2688 floats = 672 float4
        const float4* s4 = (const float4*)(sbf + (size_t)t0 * 42);
        float4* d4 = (float4*)S;
        for (int i = tid; i < 672; i += 256) d4[i] = s4[i];
    }
    for (int i = tid; i < 336; i += 256) W1l[i] = W_sbf1[i];
    __syncthreads();

    {   // basis = sbf @ W_sbf1  [64][8], 2 outputs/thread
        int tt = tid >> 2, b0 = (tid & 3) << 1;
        float s0 = 0.f, s1 = 0.f;
#pragma unroll
        for (int k = 0; k < 42; k++) {
            float v = S[tt * 42 + k];
            s0 = fmaf(v, W1l[k * 8 + b0], s0);
            s1 = fmaf(v, W1l[k * 8 + b0 + 1], s1);
        }
        B[tt * 8 + b0] = s0;
        B[tt * 8 + b0 + 1] = s1;
    }
    __syncthreads();

    // wave w handles triplets w*16..w*16+15; lane = output column 0..63
    const int wave = tid >> 6, lane = tid & 63;
    float w2[8];
#pragma unroll
    for (int k = 0; k < 8; k++) w2[k] = W_sbf2[k * 64 + lane];
    const int base_tt = wave * 16;
#pragma unroll 4
    for (int u = 0; u < 16; u++) {
        int tt = base_tt + u;
        int t = t0 + tt;
        int se = src_idx[t];
        int de = dst_idx[t];
        float acc = 0.f;
#pragma unroll
        for (int k = 0; k < 8; k++) acc = fmaf(B[tt * 8 + k], w2[k], acc);
        float xk = x_kj[(size_t)se * 64 + lane];
        atomicAdd(&m_update[(size_t)de * 64 + lane], xk * acc);
    }
}

// ---- post chain helpers ----
__device__ __forceinline__ void stage_silu_store(const float* __restrict__ Xl,
                                                 const float* __restrict__ W,
                                                 const float* __restrict__ bias,
                                                 float* __restrict__ Yl, int ty, int tx) {
    float acc[8][4];
    gemmK_128<128>(Xl, W, ty, tx, acc);
    float4 b = ((const float4*)bias)[tx];
#pragma unroll
    for (int i = 0; i < 8; i++) {
        int r = ty * 8 + i;
        float4 v;
        v.x = silu_f(acc[i][0] + b.x);
        v.y = silu_f(acc[i][1] + b.y);
        v.z = silu_f(acc[i][2] + b.z);
        v.w = silu_f(acc[i][3] + b.w);
        ((float4*)Yl)[r * 32 + tx] = v;
    }
}

__device__ __forceinline__ void stage_silu_addinto(const float* __restrict__ Xl,
                                                   const float* __restrict__ W,
                                                   const float* __restrict__ bias,
                                                   float* __restrict__ Yl, int ty, int tx) {
    float acc[8][4];
    gemmK_128<128>(Xl, W, ty, tx, acc);
    float4 b = ((const float4*)bias)[tx];
#pragma unroll
    for (int i = 0; i < 8; i++) {
        int r = ty * 8 + i;
        float4 v = ((float4*)Yl)[r * 32 + tx];
        v.x += silu_f(acc[i][0] + b.x);
        v.y += silu_f(acc[i][1] + b.y);
        v.z += silu_f(acc[i][2] + b.z);
        v.w += silu_f(acc[i][3] + b.w);
        ((float4*)Yl)[r * 32 + tx] = v;
    }
}

__global__ __launch_bounds__(256, 2) void post_kernel(
    const float* __restrict__ m, const float* __restrict__ x_ji,
    const float* __restrict__ m_up,
    const float* __restrict__ W_up,
    const float* __restrict__ Wb1, const float* __restrict__ bb1,
    const float* __restrict__ Wb2, const float* __restrict__ bb2,
    const float* __restrict__ W_final, const float* __restrict__ b_final,
    const float* __restrict__ Wa1, const float* __restrict__ ba1,
    const float* __restrict__ Wa2, const float* __restrict__ ba2,
    float* __restrict__ out) {
    __shared__ float B0[64 * 128];
    __shared__ float B1[64 * 128];
    const int tid = threadIdx.x, ty = tid >> 5, tx = tid & 31;
    const int r0 = blockIdx.x * 64;

    {   // m_update tile [64][64] packed into B0 (ld=64)
        const float4* src = (const float4*)(m_up + (size_t)r0 * 64);
        float4* dst = (float4*)B0;
#pragma unroll
        for (int i = 0; i < 4; i++) dst[tid + i * 256] = src[tid + i * 256];
    }
    __syncthreads();

    float acc[8][4];

    // s0: B1 = silu(B0[64x64] @ W_up) + x_ji
    gemmK_128<64>(B0, W_up, ty, tx, acc);
#pragma unroll
    for (int i = 0; i < 8; i++) {
        int r = ty * 8 + i;
        float4 xj = ((const float4*)x_ji)[(size_t)(r0 + r) * 32 + tx];
        float4 v;
        v.x = silu_f(acc[i][0]) + xj.x;
        v.y = silu_f(acc[i][1]) + xj.y;
        v.z = silu_f(acc[i][2]) + xj.z;
        v.w = silu_f(acc[i][3]) + xj.w;
        ((float4*)B1)[r * 32 + tx] = v;
    }
    __syncthreads();

    // s1: B0 = silu(B1 @ Wb1 + bb1)
    stage_silu_store(B1, Wb1, bb1, B0, ty, tx);
    __syncthreads();
    // s2: B1 += silu(B0 @ Wb2 + bb2)   (residual before)
    stage_silu_addinto(B0, Wb2, bb2, B1, ty, tx);
    __syncthreads();

    // s3: B0 = silu(B1 @ W_final + b_final) + m
    gemmK_128<128>(B1, W_final, ty, tx, acc);
    {
        float4 b = ((const float4*)b_final)[tx];
#pragma unroll
        for (int i = 0; i < 8; i++) {
            int r = ty * 8 + i;
            float4 mg = ((const float4*)m)[(size_t)(r0 + r) * 32 + tx];
            float4 v;
            v.x = silu_f(acc[i][0] + b.x) + mg.x;
            v.y = silu_f(acc[i][1] + b.y) + mg.y;
            v.z = silu_f(acc[i][2] + b.z) + mg.z;
            v.w = silu_f(acc[i][3] + b.w) + mg.w;
            ((float4*)B0)[r * 32 + tx] = v;
        }
    }
    __syncthreads();

    // after-residual 0
    stage_silu_store(B0, Wa1, ba1, B1, ty, tx);
    __syncthreads();
    stage_silu_addinto(B1, Wa2, ba2, B0, ty, tx);
    __syncthreads();

    // after-residual 1 (fuse final add + global store)
    stage_silu_store(B0, Wa1 + 16384, ba1 + 128, B1, ty, tx);
    __syncthreads();
    gemmK_128<128>(B1, Wa2 + 16384, ty, tx, acc);
    {
        float4 b = ((const float4*)(ba2 + 128))[tx];
#pragma unroll
        for (int i = 0; i < 8; i++) {
            int r = ty * 8 + i;
            float4 o = ((float4*)B0)[r * 32 + tx];
            o.x += silu_f(acc[i][0] + b.x);
            o.y += silu_f(acc[i][1] + b.y);
            o.z += silu_f(acc[i][2] + b.z);
            o.w += silu_f(acc[i][3] + b.w);
            ((float4*)out)[(size_t)(r0 + r) * 32 + tx] = o;
        }
    }
}

extern "C" void kernel_launch(void* const* d_in, const int* in_sizes, int n_in,
                              void* d_out, int out_size, void* d_ws, size_t ws_size,
                              hipStream_t stream) {
    const float* m      = (const float*)d_in[0];
    const float* rbf    = (const float*)d_in[1];
    const float* sbf    = (const float*)d_in[2];
    const int*   src    = (const int*)d_in[3];
    const int*   dst    = (const int*)d_in[4];
    const float* W_rbf1 = (const float*)d_in[5];
    const float* W_rbf2 = (const float*)d_in[6];
    const float* W_sbf1 = (const float*)d_in[7];
    const float* W_sbf2 = (const float*)d_in[8];
    const float* W_ji   = (const float*)d_in[9];
    const float* b_ji   = (const float*)d_in[10];
    const float* W_kj   = (const float*)d_in[11];
    const float* b_kj   = (const float*)d_in[12];
    const float* W_down = (const float*)d_in[13];
    const float* W_up   = (const float*)d_in[14];
    const float* Wb1    = (const float*)d_in[15];
    const float* bb1    = (const float*)d_in[16];
    const float* Wb2    = (const float*)d_in[17];
    const float* bb2    = (const float*)d_in[18];
    const float* W_final= (const float*)d_in[19];
    const float* b_final= (const float*)d_in[20];
    const float* Wa1    = (const float*)d_in[21];
    const float* ba1    = (const float*)d_in[22];
    const float* Wa2    = (const float*)d_in[23];
    const float* ba2    = (const float*)d_in[24];
    float* out = (float*)d_out;

    // workspace layout: x_ji [E,128] | x_kj [E,64] | m_update [E,64]  (f32)
    if (ws_size < (size_t)E_N * 256 * sizeof(float)) return;  // need 256 MiB
    float* x_ji = (float*)d_ws;
    float* x_kj = x_ji + (size_t)E_N * 128;
    float* m_up = x_kj + (size_t)E_N * 64;

    // zero m_update accumulator (ws poisoned 0xAA before every timed call)
    zero_kernel<<<(E_N * 64 / 4) / 256, 256, 0, stream>>>((float4*)m_up, E_N * 64 / 4);

    edge_kernel<<<E_N / 64, 256, 0, stream>>>(m, rbf, W_rbf1, W_rbf2, W_ji, b_ji,
                                              W_kj, b_kj, W_down, x_ji, x_kj);

    triplet_kernel<<<T_N / 64, 256, 0, stream>>>(sbf, src, dst, W_sbf1, W_sbf2,
                                                 x_kj, m_up);

    post_kernel<<<E_N / 64, 256, 0, stream>>>(m, x_ji, m_up, W_up, Wb1, bb1, Wb2, bb2,
                                              W_final, b_final, Wa1, ba1, Wa2, ba2, out);
}

// Round 2
// 1239.624 us; speedup vs baseline: 1.8218x; 1.8218x over previous
//
#include <hip/hip_runtime.h>
#include <math.h>

// InteractionPPBlock — round 2: bf16 MFMA for all dense GEMMs.
// Residual trunk kept in f32 registers (D-layout positions are wave-stable).
// Weights pre-swizzled per call into B-fragment-linear bf16 (ws is re-poisoned).
//
// MFMA layouts (m89/m101-verified):
//   A-frag: lane holds A[m=lane&15][k=(lane>>4)*8 + j], j=0..7  (one 16B chunk)
//   B-frag: lane holds B[k=(lane>>4)*8 + j][n=lane&15]
//   C/D   : col=lane&15, row=(lane>>4)*4 + reg

#define E_N 262144
#define T_N 2097152
#define LDX 136   // 128 + 8 bf16 pad -> 272B row stride (16B-aligned, banks spread)

typedef __bf16 bf16_t;
typedef __attribute__((ext_vector_type(8))) __bf16 bf16x8;
typedef __attribute__((ext_vector_type(4))) float f32x4;

#define MFMA_B16(a, b, c) __builtin_amdgcn_mfma_f32_16x16x32_bf16(a, b, c, 0, 0, 0)

__device__ __forceinline__ float silu_f(float x) {
    return x / (1.0f + __expf(-x));
}

// ---------------- weight swizzle prep ----------------
// dst layout: frag f = ct*KK + kk; element ((f*64 + lane)*8 + j) = B[kk*32+q*8+j][ct*16+c]
struct SwDesc { const float* src; bf16_t* dst; int Ksrc, KK, N, tbase; };
struct SwArgs { SwDesc d[12]; };

__global__ __launch_bounds__(256) void swizzle_kernel(SwArgs a, int total) {
    int t = blockIdx.x * 256 + threadIdx.x;
    if (t >= total) return;
    int i = 0;
#pragma unroll
    for (int j = 1; j < 12; j++) if (t >= a.d[j].tbase) i = j;
    SwDesc d = a.d[i];
    int lt = t - d.tbase;
    int lane = lt & 63, f = lt >> 6;
    int kk = f % d.KK, ct = f / d.KK;
    int q = lane >> 4, c = lane & 15, col = ct * 16 + c;
    bf16x8 v;
#pragma unroll
    for (int j = 0; j < 8; j++) {
        int k = kk * 32 + q * 8 + j;
        v[j] = (k < d.Ksrc) ? (bf16_t)d.src[(size_t)k * d.N + col] : (bf16_t)0.0f;
    }
    *(bf16x8*)(d.dst + (size_t)lt * 8) = v;
}

__global__ __launch_bounds__(256) void zero_kernel(float4* __restrict__ p, int n4) {
    int i = blockIdx.x * 256 + threadIdx.x;
    if (i < n4) p[i] = make_float4(0.f, 0.f, 0.f, 0.f);
}

// ---------------- MFMA stage: acc[rt][ctl] = X(64 x 32*KK) @ W  for this wave's 2 col-tiles
template<int KK>
__device__ __forceinline__ void mfma_stage(const bf16_t* __restrict__ X,      // LDS, stride LDX
                                           const bf16_t* __restrict__ Wsw,    // global, swizzled
                                           int lane, int ct0, f32x4 acc[4][2]) {
    const int q = lane >> 4, l15 = lane & 15;
    bf16x8 Bf[2][KK];
#pragma unroll
    for (int c = 0; c < 2; c++)
#pragma unroll
        for (int kk = 0; kk < KK; kk++)
            Bf[c][kk] = *(const bf16x8*)(Wsw + ((size_t)((ct0 + c) * KK + kk) * 64 + lane) * 8);
    f32x4 z = {0.f, 0.f, 0.f, 0.f};
#pragma unroll
    for (int rt = 0; rt < 4; rt++) { acc[rt][0] = z; acc[rt][1] = z; }
#pragma unroll
    for (int kk = 0; kk < KK; kk++) {
#pragma unroll
        for (int rt = 0; rt < 4; rt++) {
            bf16x8 a = *(const bf16x8*)(X + (rt * 16 + l15) * LDX + kk * 32 + q * 8);
            acc[rt][0] = MFMA_B16(a, Bf[0][kk], acc[rt][0]);
            acc[rt][1] = MFMA_B16(a, Bf[1][kk], acc[rt][1]);
        }
    }
}

// ---------------- edge kernel ----------------
__global__ __launch_bounds__(256, 3) void edge_kernel(
    const float* __restrict__ m, const float* __restrict__ rbf,
    const float* __restrict__ W_rbf1, const bf16_t* __restrict__ W_rbf2sw,
    const bf16_t* __restrict__ W_jisw, const float* __restrict__ b_ji,
    const bf16_t* __restrict__ W_kjsw, const float* __restrict__ b_kj,
    const bf16_t* __restrict__ W_downsw,
    bf16_t* __restrict__ x_ji_bf, float* __restrict__ x_kj) {
    __shared__ bf16_t Xm[64 * LDX];
    __shared__ bf16_t Xt[64 * LDX];
    __shared__ bf16_t hb[64 * 32];   // h zero-padded K 8->32
    __shared__ float rl[64 * 6];
    const int tid = threadIdx.x;
    const int lane = tid & 63, wave = tid >> 6;
    const int q = lane >> 4, l15 = lane & 15;
    const int ct0 = wave * 2, wc0 = wave * 32;
    const int r0 = blockIdx.x * 64;

    // stage m tile -> bf16 LDS
#pragma unroll
    for (int i = 0; i < 8; i++) {
        int e = (i * 256 + tid) * 4;
        int row = e >> 7, col = e & 127;
        float4 v = *(const float4*)(m + (size_t)(r0 + row) * 128 + col);
        bf16_t* d = Xm + row * LDX + col;
        d[0] = (bf16_t)v.x; d[1] = (bf16_t)v.y; d[2] = (bf16_t)v.z; d[3] = (bf16_t)v.w;
    }
    for (int i = tid; i < 64 * 6; i += 256) rl[i] = rbf[(size_t)r0 * 6 + i];
    for (int i = tid; i < 64 * 32; i += 256) hb[i] = (bf16_t)0.0f;
    __syncthreads();

    {   // h = rbf @ W_rbf1 [64][8] -> hb (bf16, zero-padded to K=32)
        int tt = tid >> 2, b0 = (tid & 3) << 1;
        float s0 = 0.f, s1 = 0.f;
#pragma unroll
        for (int k = 0; k < 6; k++) {
            float v = rl[tt * 6 + k];
            s0 = fmaf(v, W_rbf1[k * 8 + b0], s0);
            s1 = fmaf(v, W_rbf1[k * 8 + b0 + 1], s1);
        }
        hb[tt * 32 + b0] = (bf16_t)s0;
        hb[tt * 32 + b0 + 1] = (bf16_t)s1;
    }
    __syncthreads();

    // rbf_e = hb @ W_rbf2  (KK=1, zero-padded)
    f32x4 rbfe[4][2];
    {
        bf16x8 B0 = *(const bf16x8*)(W_rbf2sw + ((size_t)(ct0 + 0) * 64 + lane) * 8);
        bf16x8 B1 = *(const bf16x8*)(W_rbf2sw + ((size_t)(ct0 + 1) * 64 + lane) * 8);
        f32x4 z = {0.f, 0.f, 0.f, 0.f};
#pragma unroll
        for (int rt = 0; rt < 4; rt++) {
            bf16x8 a = *(const bf16x8*)(hb + (rt * 16 + l15) * 32 + q * 8);
            rbfe[rt][0] = MFMA_B16(a, B0, z);
            rbfe[rt][1] = MFMA_B16(a, B1, z);
        }
    }

    f32x4 acc[4][2];

    // x_ji = silu(m @ W_ji + b_ji) -> global bf16
    mfma_stage<4>(Xm, W_jisw, lane, ct0, acc);
    {
        float b0v = b_ji[wc0 + l15], b1v = b_ji[wc0 + 16 + l15];
#pragma unroll
        for (int rt = 0; rt < 4; rt++)
#pragma unroll
            for (int c = 0; c < 2; c++)
#pragma unroll
                for (int r = 0; r < 4; r++) {
                    int row = rt * 16 + q * 4 + r, col = wc0 + c * 16 + l15;
                    float v = silu_f(acc[rt][c][r] + (c ? b1v : b0v));
                    x_ji_bf[(size_t)(r0 + row) * 128 + col] = (bf16_t)v;
                }
    }

    // t = silu(m @ W_kj + b_kj) * rbf_e -> Xt (bf16)
    mfma_stage<4>(Xm, W_kjsw, lane, ct0, acc);
    {
        float b0v = b_kj[wc0 + l15], b1v = b_kj[wc0 + 16 + l15];
#pragma unroll
        for (int rt = 0; rt < 4; rt++)
#pragma unroll
            for (int c = 0; c < 2; c++)
#pragma unroll
                for (int r = 0; r < 4; r++) {
                    int row = rt * 16 + q * 4 + r, col = wc0 + c * 16 + l15;
                    float v = silu_f(acc[rt][c][r] + (c ? b1v : b0v)) * rbfe[rt][c][r];
                    Xt[row * LDX + col] = (bf16_t)v;
                }
    }
    __syncthreads();

    // x_kj = silu(Xt @ W_down) [64 cols]; wave handles ct = wave
    {
        bf16x8 Bf[4];
#pragma unroll
        for (int kk = 0; kk < 4; kk++)
            Bf[kk] = *(const bf16x8*)(W_downsw + ((size_t)(wave * 4 + kk) * 64 + lane) * 8);
        f32x4 a2[4];
        f32x4 z = {0.f, 0.f, 0.f, 0.f};
#pragma unroll
        for (int rt = 0; rt < 4; rt++) a2[rt] = z;
#pragma unroll
        for (int kk = 0; kk < 4; kk++)
#pragma unroll
            for (int rt = 0; rt < 4; rt++) {
                bf16x8 a = *(const bf16x8*)(Xt + (rt * 16 + l15) * LDX + kk * 32 + q * 8);
                a2[rt] = MFMA_B16(a, Bf[kk], a2[rt]);
            }
#pragma unroll
        for (int rt = 0; rt < 4; rt++)
#pragma unroll
            for (int r = 0; r < 4; r++) {
                int row = rt * 16 + q * 4 + r, col = wave * 16 + l15;
                x_kj[(size_t)(r0 + row) * 64 + col] = silu_f(a2[rt][r]);
            }
    }
}

// ---------------- triplet kernel (unchanged) ----------------
__global__ __launch_bounds__(256, 4) void triplet_kernel(
    const float* __restrict__ sbf, const int* __restrict__ src_idx,
    const int* __restrict__ dst_idx,
    const float* __restrict__ W_sbf1, const float* __restrict__ W_sbf2,
    const float* __restrict__ x_kj, float* __restrict__ m_update) {
    __shared__ float S[64 * 42];
    __shared__ float B[64 * 8];
    __shared__ float W1l[42 * 8];
    const int tid = threadIdx.x;
    const int t0 = blockIdx.x * 64;

    {
        const float4* s4 = (const float4*)(sbf + (size_t)t0 * 42);
        float4* d4 = (float4*)S;
        for (int i = tid; i < 672; i += 256) d4[i] = s4[i];
    }
    for (int i = tid; i < 336; i += 256) W1l[i] = W_sbf1[i];
    __syncthreads();

    {
        int tt = tid >> 2, b0 = (tid & 3) << 1;
        float s0 = 0.f, s1 = 0.f;
#pragma unroll
        for (int k = 0; k < 42; k++) {
            float v = S[tt * 42 + k];
            s0 = fmaf(v, W1l[k * 8 + b0], s0);
            s1 = fmaf(v, W1l[k * 8 + b0 + 1], s1);
        }
        B[tt * 8 + b0] = s0;
        B[tt * 8 + b0 + 1] = s1;
    }
    __syncthreads();

    const int wave = tid >> 6, lane = tid & 63;
    float w2[8];
#pragma unroll
    for (int k = 0; k < 8; k++) w2[k] = W_sbf2[k * 64 + lane];
    const int base_tt = wave * 16;
#pragma unroll 4
    for (int u = 0; u < 16; u++) {
        int tt = base_tt + u;
        int t = t0 + tt;
        int se = src_idx[t];
        int de = dst_idx[t];
        float acc = 0.f;
#pragma unroll
        for (int k = 0; k < 8; k++) acc = fmaf(B[tt * 8 + k], w2[k], acc);
        float xk = x_kj[(size_t)se * 64 + lane];
        atomicAdd(&m_update[(size_t)de * 64 + lane], xk * acc);
    }
}

// ---------------- post chain ----------------
__global__ __launch_bounds__(256, 3) void post_kernel(
    const float* __restrict__ m, const bf16_t* __restrict__ x_ji_bf,
    const float* __restrict__ m_up,
    const bf16_t* __restrict__ W_upsw,
    const bf16_t* __restrict__ Wb1sw, const float* __restrict__ bb1,
    const bf16_t* __restrict__ Wb2sw, const float* __restrict__ bb2,
    const bf16_t* __restrict__ Wfinsw, const float* __restrict__ b_final,
    const bf16_t* __restrict__ Wa1s0, const bf16_t* __restrict__ Wa1s1,
    const float* __restrict__ ba1,
    const bf16_t* __restrict__ Wa2s0, const bf16_t* __restrict__ Wa2s1,
    const float* __restrict__ ba2,
    float* __restrict__ out) {
    __shared__ bf16_t X0[64 * LDX];
    __shared__ bf16_t X1[64 * LDX];
    const int tid = threadIdx.x;
    const int lane = tid & 63, wave = tid >> 6;
    const int q = lane >> 4, l15 = lane & 15;
    const int ct0 = wave * 2, wc0 = wave * 32;
    const int r0 = blockIdx.x * 64;

    // stage m_up [64][64] f32 -> bf16 X0
#pragma unroll
    for (int i = 0; i < 4; i++) {
        int e = (i * 256 + tid) * 4;
        int row = e >> 6, col = e & 63;
        float4 v = *(const float4*)(m_up + (size_t)(r0 + row) * 64 + col);
        bf16_t* d = X0 + row * LDX + col;
        d[0] = (bf16_t)v.x; d[1] = (bf16_t)v.y; d[2] = (bf16_t)v.z; d[3] = (bf16_t)v.w;
    }
    __syncthreads();

    f32x4 acc[4][2];
    float res[4][2][4];

    // s0: U = silu(X0 @ W_up) + x_ji ; res=U ; X1=bf16(U)
    mfma_stage<2>(X0, W_upsw, lane, ct0, acc);
#pragma unroll
    for (int rt = 0; rt < 4; rt++)
#pragma unroll
        for (int c = 0; c < 2; c++)
#pragma unroll
            for (int r = 0; r < 4; r++) {
                int row = rt * 16 + q * 4 + r, col = wc0 + c * 16 + l15;
                float v = silu_f(acc[rt][c][r]) + (float)x_ji_bf[(size_t)(r0 + row) * 128 + col];
                res[rt][c][r] = v;
                X1[row * LDX + col] = (bf16_t)v;
            }
    __syncthreads();

    // s1: H1 = silu(X1 @ Wb1 + bb1) -> X0
    mfma_stage<4>(X1, Wb1sw, lane, ct0, acc);
    {
        float b0v = bb1[wc0 + l15], b1v = bb1[wc0 + 16 + l15];
#pragma unroll
        for (int rt = 0; rt < 4; rt++)
#pragma unroll
            for (int c = 0; c < 2; c++)
#pragma unroll
                for (int r = 0; r < 4; r++) {
                    int row = rt * 16 + q * 4 + r, col = wc0 + c * 16 + l15;
                    X0[row * LDX + col] = (bf16_t)silu_f(acc[rt][c][r] + (c ? b1v : b0v));
                }
    }
    __syncthreads();

    // s2: res += silu(X0 @ Wb2 + bb2) ; X1 = bf16(res)
    mfma_stage<4>(X0, Wb2sw, lane, ct0, acc);
    {
        float b0v = bb2[wc0 + l15], b1v = bb2[wc0 + 16 + l15];
#pragma unroll
        for (int rt = 0; rt < 4; rt++)
#pragma unroll
            for (int c = 0; c < 2; c++)
#pragma unroll
                for (int r = 0; r < 4; r++) {
                    int row = rt * 16 + q * 4 + r, col = wc0 + c * 16 + l15;
                    float v = res[rt][c][r] + silu_f(acc[rt][c][r] + (c ? b1v : b0v));
                    res[rt][c][r] = v;
                    X1[row * LDX + col] = (bf16_t)v;
                }
    }
    __syncthreads();

    // s3: res = silu(X1 @ W_final + b_final) + m ; X0 = bf16(res)
    mfma_stage<4>(X1, Wfinsw, lane, ct0, acc);
    {
        float b0v = b_final[wc0 + l15], b1v = b_final[wc0 + 16 + l15];
#pragma unroll
        for (int rt = 0; rt < 4; rt++)
#pragma unroll
            for (int c = 0; c < 2; c++)
#pragma unroll
                for (int r = 0; r < 4; r++) {
                    int row = rt * 16 + q * 4 + r, col = wc0 + c * 16 + l15;
                    float v = silu_f(acc[rt][c][r] + (c ? b1v : b0v))
                              + m[(size_t)(r0 + row) * 128 + col];
                    res[rt][c][r] = v;
                    X0[row * LDX + col] = (bf16_t)v;
                }
    }
    __syncthreads();

    // s4: H = silu(X0 @ Wa1[0] + ba1[0]) -> X1
    mfma_stage<4>(X0, Wa1s0, lane, ct0, acc);
    {
        float b0v = ba1[wc0 + l15], b1v = ba1[wc0 + 16 + l15];
#pragma unroll
        for (int rt = 0; rt < 4; rt++)
#pragma unroll
            for (int c = 0; c < 2; c++)
#pragma unroll
                for (int r = 0; r < 4; r++) {
                    int row = rt * 16 + q * 4 + r, col = wc0 + c * 16 + l15;
                    X1[row * LDX + col] = (bf16_t)silu_f(acc[rt][c][r] + (c ? b1v : b0v));
                }
    }
    __syncthreads();

    // s5: res += silu(X1 @ Wa2[0] + ba2[0]) ; X0 = bf16(res)
    mfma_stage<4>(X1, Wa2s0, lane, ct0, acc);
    {
        float b0v = ba2[wc0 + l15], b1v = ba2[wc0 + 16 + l15];
#pragma unroll
        for (int rt = 0; rt < 4; rt++)
#pragma unroll
            for (int c = 0; c < 2; c++)
#pragma unroll
                for (int r = 0; r < 4; r++) {
                    int row = rt * 16 + q * 4 + r, col = wc0 + c * 16 + l15;
                    float v = res[rt][c][r] + silu_f(acc[rt][c][r] + (c ? b1v : b0v));
                    res[rt][c][r] = v;
                    X0[row * LDX + col] = (bf16_t)v;
                }
    }
    __syncthreads();

    // s6: H = silu(X0 @ Wa1[1] + ba1[1]) -> X1
    mfma_stage<4>(X0, Wa1s1, lane, ct0, acc);
    {
        float b0v = ba1[128 + wc0 + l15], b1v = ba1[128 + wc0 + 16 + l15];
#pragma unroll
        for (int rt = 0; rt < 4; rt++)
#pragma unroll
            for (int c = 0; c < 2; c++)
#pragma unroll
                for (int r = 0; r < 4; r++) {
                    int row = rt * 16 + q * 4 + r, col = wc0 + c * 16 + l15;
                    X1[row * LDX + col] = (bf16_t)silu_f(acc[rt][c][r] + (c ? b1v : b0v));
                }
    }
    __syncthreads();

    // s7: out = res + silu(X1 @ Wa2[1] + ba2[1])
    mfma_stage<4>(X1, Wa2s1, lane, ct0, acc);
    {
        float b0v = ba2[128 + wc0 + l15], b1v = ba2[128 + wc0 + 16 + l15];
#pragma unroll
        for (int rt = 0; rt < 4; rt++)
#pragma unroll
            for (int c = 0; c < 2; c++)
#pragma unroll
                for (int r = 0; r < 4; r++) {
                    int row = rt * 16 + q * 4 + r, col = wc0 + c * 16 + l15;
                    out[(size_t)(r0 + row) * 128 + col]
                        = res[rt][c][r] + silu_f(acc[rt][c][r] + (c ? b1v : b0v));
                }
    }
}

extern "C" void kernel_launch(void* const* d_in, const int* in_sizes, int n_in,
                              void* d_out, int out_size, void* d_ws, size_t ws_size,
                              hipStream_t stream) {
    const float* m      = (const float*)d_in[0];
    const float* rbf    = (const float*)d_in[1];
    const float* sbf    = (const float*)d_in[2];
    const int*   src    = (const int*)d_in[3];
    const int*   dst    = (const int*)d_in[4];
    const float* W_rbf1 = (const float*)d_in[5];
    const float* W_rbf2 = (const float*)d_in[6];
    const float* W_sbf1 = (const float*)d_in[7];
    const float* W_sbf2 = (const float*)d_in[8];
    const float* W_ji   = (const float*)d_in[9];
    const float* b_ji   = (const float*)d_in[10];
    const float* W_kj   = (const float*)d_in[11];
    const float* b_kj   = (const float*)d_in[12];
    const float* W_down = (const float*)d_in[13];
    const float* W_up   = (const float*)d_in[14];
    const float* Wb1    = (const float*)d_in[15];
    const float* bb1    = (const float*)d_in[16];
    const float* Wb2    = (const float*)d_in[17];
    const float* bb2    = (const float*)d_in[18];
    const float* W_final= (const float*)d_in[19];
    const float* b_final= (const float*)d_in[20];
    const float* Wa1    = (const float*)d_in[21];
    const float* ba1    = (const float*)d_in[22];
    const float* Wa2    = (const float*)d_in[23];
    const float* ba2    = (const float*)d_in[24];
    float* out = (float*)d_out;

    // ws layout: x_ji bf16 [E,128] | x_kj f32 [E,64] | m_update f32 [E,64] | swizzled weights
    size_t off_xkj = (size_t)E_N * 128 * sizeof(bf16_t);
    size_t off_mup = off_xkj + (size_t)E_N * 64 * sizeof(float);
    size_t off_w   = off_mup + (size_t)E_N * 64 * sizeof(float);
    size_t w_elems = 167936;
    if (ws_size < off_w + w_elems * sizeof(bf16_t)) return;

    bf16_t* x_ji_bf = (bf16_t*)d_ws;
    float*  x_kj    = (float*)((char*)d_ws + off_xkj);
    float*  m_upd   = (float*)((char*)d_ws + off_mup);
    bf16_t* wts     = (bf16_t*)((char*)d_ws + off_w);

    bf16_t* W_rbf2sw = wts;            // 8 frags   (K 8->32 pad, N=128)
    bf16_t* W_jisw   = wts + 4096;     // 32 frags
    bf16_t* W_kjsw   = wts + 20480;    // 32
    bf16_t* W_downsw = wts + 36864;    // 16 (K=128, N=64)
    bf16_t* W_upsw   = wts + 45056;    // 16 (K=64, N=128)
    bf16_t* Wb1sw    = wts + 53248;
    bf16_t* Wb2sw    = wts + 69632;
    bf16_t* Wfinsw   = wts + 86016;
    bf16_t* Wa1sw0   = wts + 102400;
    bf16_t* Wa1sw1   = wts + 118784;
    bf16_t* Wa2sw0   = wts + 135168;
    bf16_t* Wa2sw1   = wts + 151552;

    SwArgs sa;
    int tb = 0;
    auto set = [&](int i, const float* s, bf16_t* d, int Ksrc, int KK, int N) {
        sa.d[i] = SwDesc{s, d, Ksrc, KK, N, tb};
        tb += (N / 16) * KK * 64;
    };
    set(0,  W_rbf2,        W_rbf2sw, 8,   1, 128);
    set(1,  W_ji,          W_jisw,   128, 4, 128);
    set(2,  W_kj,          W_kjsw,   128, 4, 128);
    set(3,  W_down,        W_downsw, 128, 4, 64);
    set(4,  W_up,          W_upsw,   64,  2, 128);
    set(5,  Wb1,           Wb1sw,    128, 4, 128);
    set(6,  Wb2,           Wb2sw,    128, 4, 128);
    set(7,  W_final,       Wfinsw,   128, 4, 128);
    set(8,  Wa1,           Wa1sw0,   128, 4, 128);
    set(9,  Wa1 + 16384,   Wa1sw1,   128, 4, 128);
    set(10, Wa2,           Wa2sw0,   128, 4, 128);
    set(11, Wa2 + 16384,   Wa2sw1,   128, 4, 128);
    int total = tb;  // 20992

    swizzle_kernel<<<(total + 255) / 256, 256, 0, stream>>>(sa, total);

    zero_kernel<<<(E_N * 64 / 4) / 256, 256, 0, stream>>>((float4*)m_upd, E_N * 64 / 4);

    edge_kernel<<<E_N / 64, 256, 0, stream>>>(m, rbf, W_rbf1, W_rbf2sw,
                                              W_jisw, b_ji, W_kjsw, b_kj, W_downsw,
                                              x_ji_bf, x_kj);

    triplet_kernel<<<T_N / 64, 256, 0, stream>>>(sbf, src, dst, W_sbf1, W_sbf2,
                                                 x_kj, m_upd);

    post_kernel<<<E_N / 64, 256, 0, stream>>>(m, x_ji_bf, m_upd, W_upsw,
                                              Wb1sw, bb1, Wb2sw, bb2,
                                              Wfinsw, b_final,
                                              Wa1sw0, Wa1sw1, ba1,
                                              Wa2sw0, Wa2sw1, ba2, out);
}